// Round 3
// baseline (275.885 us; speedup 1.0000x reference)
//
#include <hip/hip_runtime.h>
#include <stdint.h>

#define B_      16
#define F_      257
#define T_      8000
#define NB_     64
#define TT_     64
#define NTILES  125
#define TPC     2      // body tiles per chunk
#define NCHUNK  64     // 16 b x 64 chunks = 1024 blocks = 4 blocks/CU
#define WTILES  2      // warm-up tiles (128 steps; contraction 0.9526^128 ~ 2e-3)
#define LD      264    // LDS leading dim (uint16): 528B/row ≡ 4-bank rotation per row

typedef __attribute__((ext_vector_type(8))) short short8;
typedef __attribute__((ext_vector_type(4))) float floatx4;

__device__ __forceinline__ unsigned short f2bf(float x) {
    union { float f; unsigned u; } v; v.f = x;
    unsigned r = v.u + 0x7FFFu + ((v.u >> 16) & 1u);   // RNE
    return (unsigned short)(r >> 16);
}
__device__ __forceinline__ float bf2f(unsigned short h) {
    union { float f; unsigned u; } v; v.u = ((unsigned)h) << 16;
    return v.f;
}

// LDS tile: conceptual bf16 [t in 0..63][f in 0..255], physical uint16 index:
//   idx16(t,f) = t*LD + (f ^ ((t&15)<<3))
// - swizzle at 8-element (16B) granularity -> einsum b128 frag loads stay contiguous+aligned
// - scan access (fixed t, lanes=f): XOR is a bijection on [0,256) -> conflict-free
// - LD=264 rotates banks by 4 per t-row to spread staging-write/einsum-read conflicts

__global__ __launch_bounds__(256, 4) void vnr_fused_kernel(
    const float* __restrict__ mag, const float* __restrict__ fb,
    const float* __restrict__ p_ns, const float* __restrict__ p_rr,
    const float* __restrict__ p_rf, float* __restrict__ out)
{
    __shared__ unsigned short tile16[64 * LD];   // 33 KB
    __shared__ float mag256s[64];
    __shared__ float vnr256s[64];

    const int tid  = threadIdx.x;
    const int lane = tid & 63;
    const int w    = tid >> 6;          // wave 0..3
    const int l15  = tid & 15;
    const int q    = (tid & 63) >> 4;   // quad in wave

    const int bid = blockIdx.x;
    const int b   = bid & 15;
    const int c   = bid >> 4;           // chunk 0..63

    const float ns   = fabsf(p_ns[0]);
    const float rise = 1.0f / (1.0f + __expf(-p_rr[0]));
    const float fall = 1.0f / (1.0f + __expf(-p_rf[0]));

    const float* magp = mag + (size_t)b * (size_t)F_ * (size_t)T_;

    // ---- A-operand fragments (fb) straight into VGPRs, bf16-packed ----
    // lane holds A[m = 16w + l15][f = 32*kt + 8q + j], j=0..7
    short8 afrag[8];
    {
        const float* fbrow = fb + (16 * w + l15) * F_;
        #pragma unroll
        for (int kt = 0; kt < 8; ++kt) {
            const int f0 = 32 * kt + 8 * q;
            short8 a;
            #pragma unroll
            for (int j = 0; j < 8; ++j) a[j] = (short)f2bf(fbrow[f0 + j]);
            afrag[kt] = a;
        }
    }
    // fb[:,256] for the scalar fixup: rows 16w + 4q + r  (matches D layout)
    float fb256[4];
    #pragma unroll
    for (int r = 0; r < 4; ++r) fb256[r] = fb[(16 * w + 4 * q + r) * F_ + 256];

    // ---- init_min over first 20 frames (exact, like reference) ----
    const int f_own = tid;
    float mn = 1e30f;
    #pragma unroll
    for (int t = 0; t < 20; ++t) mn = fminf(mn, magp[(size_t)f_own * T_ + t]);
    const float initv  = fmaxf(mn, 1e-5f);
    const float floorv = 0.5f * initv;
    float nf = initv;

    float nf256 = 0.f, floor256 = 0.f;
    if (tid == 0) {
        float m2 = 1e30f;
        for (int t = 0; t < 20; ++t) m2 = fminf(m2, magp[(size_t)256 * T_ + t]);
        float iv = fmaxf(m2, 1e-5f);
        nf256 = iv; floor256 = 0.5f * iv;
    }

    const int bodyBeg = TPC * c;
    const int tileBeg = (c == 0) ? 0 : max(0, bodyBeg - WTILES);
    const int tileEnd = min(bodyBeg + TPC, NTILES);

    for (int tile = tileBeg; tile < tileEnd; ++tile) {
        const bool body = (tile >= bodyBeg);
        const int t0 = tile * TT_;

        __syncthreads();   // protect tile16 from previous einsum readers
        // ---- stage mag tile: 16 passes x 16 rows, one float4 (4 consecutive t) per thread ----
        // pass i: thread tid stages row f = i*16 + (tid>>4), t in [4*(tid&15), +4)
        // 16 thr/row x 16 rows = 256 thr; 16 passes cover all 256 rows. 256B/row segments coalesce.
        #pragma unroll 4
        for (int i = 0; i < 16; ++i) {
            const int f  = i * 16 + (tid >> 4);
            const int tl = (tid & 15) * 4;
            const float4 g = *(const float4*)&magp[(size_t)f * T_ + (t0 + tl)];
            tile16[(tl + 0) * LD + (f ^ (((tl + 0) & 15) << 3))] = f2bf(g.x);
            tile16[(tl + 1) * LD + (f ^ (((tl + 1) & 15) << 3))] = f2bf(g.y);
            tile16[(tl + 2) * LD + (f ^ (((tl + 2) & 15) << 3))] = f2bf(g.z);
            tile16[(tl + 3) * LD + (f ^ (((tl + 3) & 15) << 3))] = f2bf(g.w);
        }
        if (w == 0) mag256s[lane] = magp[(size_t)256 * T_ + (t0 + lane)];
        __syncthreads();

        // ---- sequential scan (thread owns f = tid), vnr written in place ----
        {
            float nfl = nf;
            if (body) {
                #pragma unroll 4
                for (int j = 0; j < 64; ++j) {
                    const int idx = j * LD + (f_own ^ ((j & 15) << 3));
                    const float x = bf2f(tile16[idx]);
                    const float a = (x > nfl) ? rise : fall;
                    nfl = fmaxf(nfl + a * (x - nfl), floorv);
                    const float vnr = x * __builtin_amdgcn_rcpf(ns * nfl + 1e-8f);
                    tile16[idx] = f2bf(vnr);
                }
            } else {
                #pragma unroll 4
                for (int j = 0; j < 64; ++j) {
                    const float x = bf2f(tile16[j * LD + (f_own ^ ((j & 15) << 3))]);
                    const float a = (x > nfl) ? rise : fall;
                    nfl = fmaxf(nfl + a * (x - nfl), floorv);
                }
            }
            nf = nfl;
            if (tid == 0) {   // f = 256 sequence (fp32 column)
                float nl = nf256;
                for (int j = 0; j < 64; ++j) {
                    const float x = mag256s[j];
                    const float a = (x > nl) ? rise : fall;
                    nl = fmaxf(nl + a * (x - nl), floor256);
                    if (body) vnr256s[j] = x * __builtin_amdgcn_rcpf(ns * nl + 1e-8f);
                }
                nf256 = nl;
            }
        }
        if (!body) continue;
        __syncthreads();

        // ---- einsum: out[n,t] = tanh(0.1 * sum_f fb[n,f]*vnr[f,t]) via MFMA ----
        floatx4 acc[4];
        #pragma unroll
        for (int tt = 0; tt < 4; ++tt) acc[tt] = (floatx4){0.f, 0.f, 0.f, 0.f};

        #pragma unroll
        for (int kt = 0; kt < 8; ++kt) {
            #pragma unroll
            for (int tt = 0; tt < 4; ++tt) {
                const int t = tt * 16 + l15;
                const short8* bp = (const short8*)
                    &tile16[t * LD + ((32 * kt + 8 * q) ^ (l15 << 3))];
                acc[tt] = __builtin_amdgcn_mfma_f32_16x16x32_bf16(afrag[kt], *bp, acc[tt], 0, 0, 0);
            }
        }

        const size_t outb = (size_t)b * NB_ * T_;
        #pragma unroll
        for (int tt = 0; tt < 4; ++tt) {
            const int t = tt * 16 + l15;
            const float v256 = vnr256s[t];
            #pragma unroll
            for (int r = 0; r < 4; ++r) {
                const float s = acc[tt][r] + fb256[r] * v256;        // s >= 0
                const float e = __expf(s * 0.2f);                    // e^(2*s/10)
                const float y = 1.0f - 2.0f * __builtin_amdgcn_rcpf(e + 1.0f);  // tanh(s/10)
                out[outb + (size_t)(16 * w + 4 * q + r) * T_ + (size_t)(t0 + t)] = y;
            }
        }
    }
}

extern "C" void kernel_launch(void* const* d_in, const int* in_sizes, int n_in,
                              void* d_out, int out_size, void* d_ws, size_t ws_size,
                              hipStream_t stream) {
    (void)in_sizes; (void)n_in; (void)d_ws; (void)ws_size; (void)out_size;
    const float* mag = (const float*)d_in[0];
    const float* fb  = (const float*)d_in[1];
    const float* ns  = (const float*)d_in[2];
    const float* rr  = (const float*)d_in[3];
    const float* rf  = (const float*)d_in[4];
    float* out = (float*)d_out;

    dim3 grid(B_ * NCHUNK);   // 1024 blocks = 16 b x 64 chunks -> 4 blocks/CU
    dim3 block(256);
    hipLaunchKernelGGL(vnr_fused_kernel, grid, block, 0, stream, mag, fb, ns, rr, rf, out);
}

// Round 4
// 249.927 us; speedup vs baseline: 1.1039x; 1.1039x over previous
//
#include <hip/hip_runtime.h>
#include <stdint.h>

#define B_      16
#define F_      257
#define T_      8000
#define NB_     64
#define TT_     64
#define NTILES  125
#define TPC     2      // body tiles per chunk
#define NCHUNK  64     // 16 b x 64 chunks = 1024 blocks = 4 blocks/CU
#define WTILES  2      // warm-up tiles (128 steps; contraction 0.9526^128 ~ 2e-3)

typedef __attribute__((ext_vector_type(8))) short short8;
typedef __attribute__((ext_vector_type(4))) float floatx4;

__device__ __forceinline__ unsigned short f2bf(float x) {
    union { float f; unsigned u; } v; v.f = x;
    unsigned r = v.u + 0x7FFFu + ((v.u >> 16) & 1u);   // RNE
    return (unsigned short)(r >> 16);
}
__device__ __forceinline__ float bf2f(unsigned short h) {
    union { float f; unsigned u; } v; v.u = ((unsigned)h) << 16;
    return v.f;
}

// LDS tile: conceptual bf16 [t 0..63][f 0..255], physical uint16 index:
//   idx16(t,f) = t*256 + (f ^ (st(t)<<3)),  st(t) = ((t&3)<<2) | ((t>>2)&3)
// - 16B-granular swizzle -> einsum b128 frag loads contiguous + aligned
// - scan (row uniform, f=lane): XOR bijection -> 64 consecutive uint16 -> 2-way free
// - st(t) rotates the XOR with t's LOW bits swapped so staging writes (t = 4s+k,
//   k fixed per instr) get bank rotation from s -> 4-way instead of 8/16-way
// - einsum reads: group = ((4kt+q) ^ st)&7, st&7 uniform over l15 -> balanced
__device__ __forceinline__ int stidx(int t, int f) {
    const int st = ((t & 3) << 2) | ((t >> 2) & 3);
    return t * 256 + (f ^ (st << 3));
}

__global__ __launch_bounds__(256, 4) void vnr_fused_kernel(
    const float* __restrict__ mag, const float* __restrict__ fb,
    const float* __restrict__ p_ns, const float* __restrict__ p_rr,
    const float* __restrict__ p_rf, float* __restrict__ out)
{
    __shared__ unsigned short tile16[64 * 256];   // 32 KB
    __shared__ float mag256s[64];
    __shared__ float vnr256s[64];

    const int tid  = threadIdx.x;
    const int lane = tid & 63;
    const int w    = tid >> 6;          // wave 0..3
    const int l15  = tid & 15;
    const int q    = (tid & 63) >> 4;   // quad in wave

    const int bid = blockIdx.x;
    const int b   = bid & 15;
    const int c   = bid >> 4;           // chunk 0..63

    const float ns   = fabsf(p_ns[0]);
    const float rise = 1.0f / (1.0f + __expf(-p_rr[0]));
    const float fall = 1.0f / (1.0f + __expf(-p_rf[0]));

    const float* magp = mag + (size_t)b * (size_t)F_ * (size_t)T_;

    // ---- A-operand fragments (fb) straight into VGPRs, bf16-packed ----
    // lane holds A[m = 16w + l15][f = 32*kt + 8q + j], j=0..7
    short8 afrag[8];
    {
        const float* fbrow = fb + (16 * w + l15) * F_;
        #pragma unroll
        for (int kt = 0; kt < 8; ++kt) {
            const int f0 = 32 * kt + 8 * q;
            short8 a;
            #pragma unroll
            for (int j = 0; j < 8; ++j) a[j] = (short)f2bf(fbrow[f0 + j]);
            afrag[kt] = a;
        }
    }
    // fb[:,256] for the scalar fixup: rows 16w + 4q + r  (matches D layout)
    float fb256[4];
    #pragma unroll
    for (int r = 0; r < 4; ++r) fb256[r] = fb[(16 * w + 4 * q + r) * F_ + 256];

    // ---- init_min over first 20 frames (exact, like reference) ----
    const int f_own = tid;
    float mn = 1e30f;
    #pragma unroll
    for (int t = 0; t < 20; ++t) mn = fminf(mn, magp[(size_t)f_own * T_ + t]);
    const float initv  = fmaxf(mn, 1e-5f);
    const float floorv = 0.5f * initv;
    float nf = initv;

    float nf256 = 0.f, floor256 = 0.f;
    if (tid == 0) {
        float m2 = 1e30f;
        for (int t = 0; t < 20; ++t) m2 = fminf(m2, magp[(size_t)256 * T_ + t]);
        float iv = fmaxf(m2, 1e-5f);
        nf256 = iv; floor256 = 0.5f * iv;
    }

    const int bodyBeg = TPC * c;
    const int tileBeg = (c == 0) ? 0 : max(0, bodyBeg - WTILES);
    const int tileEnd = min(bodyBeg + TPC, NTILES);

    for (int tile = tileBeg; tile < tileEnd; ++tile) {
        const bool body = (tile >= bodyBeg);
        const int t0 = tile * TT_;

        __syncthreads();   // protect tile16 from previous einsum readers
        // ---- stage mag tile: 8 passes; thread owns f-pair p = i*16 + (tid>>4),
        //      t-quad s = tid&15. Two float4 loads (rows 2p, 2p+1), 4 packed b32
        //      LDS writes (bf16 pair (f,f+1) per t). 256B/row segments coalesce.
        #pragma unroll 4
        for (int i = 0; i < 8; ++i) {
            const int p = i * 16 + (tid >> 4);
            const int s = tid & 15;
            const float4 ga = *(const float4*)&magp[(size_t)(2 * p)     * T_ + (t0 + 4 * s)];
            const float4 gb = *(const float4*)&magp[(size_t)(2 * p + 1) * T_ + (t0 + 4 * s)];
            #pragma unroll
            for (int k = 0; k < 4; ++k) {
                const int t = 4 * s + k;
                const float xa = (&ga.x)[k];
                const float xb = (&gb.x)[k];
                const unsigned pack = (unsigned)f2bf(xa) | ((unsigned)f2bf(xb) << 16);
                *(unsigned*)&tile16[stidx(t, 2 * p)] = pack;   // idx even: xor has no bit0
            }
        }
        if (w == 0) mag256s[lane] = magp[(size_t)256 * T_ + (t0 + lane)];
        __syncthreads();

        // ---- sequential scan (thread owns f = tid), batched 16-wide:
        //      16 reads -> one wait -> 16 recurrence steps (-> 16 writes if body).
        //      Breaks the per-iteration LDS round-trip serialization.
        {
            float nfl = nf;
            if (body) {
                #pragma unroll
                for (int jb = 0; jb < 64; jb += 16) {
                    unsigned short xs[16];
                    #pragma unroll
                    for (int u = 0; u < 16; ++u)
                        xs[u] = tile16[stidx(jb + u, f_own)];
                    #pragma unroll
                    for (int u = 0; u < 16; ++u) {
                        const float x = bf2f(xs[u]);
                        const float a = (x > nfl) ? rise : fall;
                        nfl = fmaxf(__builtin_fmaf(a, x - nfl, nfl), floorv);
                        const float vnr = x * __builtin_amdgcn_rcpf(ns * nfl + 1e-8f);
                        tile16[stidx(jb + u, f_own)] = f2bf(vnr);
                    }
                }
            } else {
                #pragma unroll
                for (int jb = 0; jb < 64; jb += 16) {
                    unsigned short xs[16];
                    #pragma unroll
                    for (int u = 0; u < 16; ++u)
                        xs[u] = tile16[stidx(jb + u, f_own)];
                    #pragma unroll
                    for (int u = 0; u < 16; ++u) {
                        const float x = bf2f(xs[u]);
                        const float a = (x > nfl) ? rise : fall;
                        nfl = fmaxf(__builtin_fmaf(a, x - nfl, nfl), floorv);
                    }
                }
            }
            nf = nfl;
            if (tid == 0) {   // f = 256 sequence (fp32 column)
                float nl = nf256;
                for (int j = 0; j < 64; ++j) {
                    const float x = mag256s[j];
                    const float a = (x > nl) ? rise : fall;
                    nl = fmaxf(__builtin_fmaf(a, x - nl, nl), floor256);
                    if (body) vnr256s[j] = x * __builtin_amdgcn_rcpf(ns * nl + 1e-8f);
                }
                nf256 = nl;
            }
        }
        if (!body) continue;
        __syncthreads();

        // ---- einsum: out[n,t] = tanh(0.1 * sum_f fb[n,f]*vnr[f,t]) via MFMA ----
        const int stl3 = ((((l15 & 3) << 2) | (l15 >> 2)) << 3);  // st(t)<<3, t&15==l15
        floatx4 acc[4];
        #pragma unroll
        for (int tt = 0; tt < 4; ++tt) acc[tt] = (floatx4){0.f, 0.f, 0.f, 0.f};

        #pragma unroll
        for (int kt = 0; kt < 8; ++kt) {
            #pragma unroll
            for (int tt = 0; tt < 4; ++tt) {
                const int t = tt * 16 + l15;
                const short8* bp = (const short8*)
                    &tile16[t * 256 + ((32 * kt + 8 * q) ^ stl3)];
                acc[tt] = __builtin_amdgcn_mfma_f32_16x16x32_bf16(afrag[kt], *bp, acc[tt], 0, 0, 0);
            }
        }

        const size_t outb = (size_t)b * NB_ * T_;
        #pragma unroll
        for (int tt = 0; tt < 4; ++tt) {
            const int t = tt * 16 + l15;
            const float v256 = vnr256s[t];
            #pragma unroll
            for (int r = 0; r < 4; ++r) {
                const float s = acc[tt][r] + fb256[r] * v256;        // s >= 0
                const float e = __expf(s * 0.2f);                    // e^(2*s/10)
                const float y = 1.0f - 2.0f * __builtin_amdgcn_rcpf(e + 1.0f);  // tanh(s/10)
                out[outb + (size_t)(16 * w + 4 * q + r) * T_ + (size_t)(t0 + t)] = y;
            }
        }
    }
}

extern "C" void kernel_launch(void* const* d_in, const int* in_sizes, int n_in,
                              void* d_out, int out_size, void* d_ws, size_t ws_size,
                              hipStream_t stream) {
    (void)in_sizes; (void)n_in; (void)d_ws; (void)ws_size; (void)out_size;
    const float* mag = (const float*)d_in[0];
    const float* fb  = (const float*)d_in[1];
    const float* ns  = (const float*)d_in[2];
    const float* rr  = (const float*)d_in[3];
    const float* rf  = (const float*)d_in[4];
    float* out = (float*)d_out;

    dim3 grid(B_ * NCHUNK);   // 1024 blocks = 16 b x 64 chunks -> 4 blocks/CU
    dim3 block(256);
    hipLaunchKernelGGL(vnr_fused_kernel, grid, block, 0, stream, mag, fb, ns, rr, rf, out);
}